// Round 4
// baseline (309.752 us; speedup 1.0000x reference)
//
#include <hip/hip_runtime.h>
#include <cstdint>

#define NPTS   16384
#define BATCH  4
#define BNP    65536
#define CIN    64
#define KNB    16
#define COUT   128
#define BN_EPS 1e-5f

typedef __attribute__((ext_vector_type(8))) short     short8;
typedef __attribute__((ext_vector_type(4))) float     f32x4;
typedef __attribute__((ext_vector_type(2))) unsigned  u32x2;
typedef __attribute__((ext_vector_type(4))) int       i32x4;

// wait until <= n vector-memory ops outstanding (lgkm=15, exp=7 = no wait)
#define WAITVM(n) __builtin_amdgcn_s_waitcnt(0x0F70 | (n))

__device__ __forceinline__ unsigned short f2bf(float f) {   // RNE
    unsigned u = __float_as_uint(f);
    u += 0x7FFFu + ((u >> 16) & 1u);
    return (unsigned short)(u >> 16);
}
__device__ __forceinline__ float bf2f(unsigned short h) {
    return __uint_as_float(((unsigned)h) << 16);
}

// ---- K0: feature [B][C][N] -> flat bf16 [B*N][64]; blk 1024: stat + weight cvt ----
__global__ __launch_bounds__(256) void k_prep(const float* __restrict__ feat,
                                              unsigned short* __restrict__ fb,
                                              float* __restrict__ stat,
                                              const float* __restrict__ Wm,
                                              const float* __restrict__ Wc,
                                              unsigned short* __restrict__ wmb,
                                              unsigned short* __restrict__ wcb)
{
    if (blockIdx.x == 1024) {           // aux block: zero BN accum, bf16-ify weights
        stat[threadIdx.x] = 0.f;        // 256 floats: [0..127]=sum, [128..255]=sumsq
        #pragma unroll
        for (int i = threadIdx.x; i < CIN * CIN; i += 256)       wmb[i] = f2bf(Wm[i]);
        #pragma unroll
        for (int i = threadIdx.x; i < COUT * CIN; i += 256)      wcb[i] = f2bf(Wc[i]);
        return;
    }
    __shared__ float t[CIN][CIN + 1];
    int blk = blockIdx.x;
    int b   = blk >> 8;
    int n0  = (blk & 255) << 6;
    int sub = threadIdx.x >> 6, lane = threadIdx.x & 63;
    const float* fp = feat + (size_t)b * CIN * NPTS;
    #pragma unroll
    for (int r = 0; r < CIN; r += 4) {
        int c = r + sub;
        t[c][lane] = fp[(size_t)c * NPTS + n0 + lane];     // coalesced along n
    }
    __syncthreads();
    unsigned short* ob = fb + (size_t)(b * NPTS + n0) * CIN;
    #pragma unroll
    for (int r = 0; r < CIN; r += 4) {
        int x = r + sub;
        ob[(size_t)x * CIN + lane] = f2bf(t[lane][x]);     // row n0+x, ch=lane
    }
}

// ---------------- K1: gather+attention+pool (per wave: 16 pts x 16 neigh) --------------
// grid 1024, 1 group per wave (4 groups = 64 consecutive points per block).
// waves_per_eu(4,4): pin exactly 4 waves/EU -> VGPR cap 128, and the allocator
// must NOT shrink to 64 for 8 waves (round-2 pathology: 64 VGPR + 350 MB spill).
// LDS = spir only (32 KB). Indices in registers (shuffle-broadcast); weights bf16.
// Epilogue: acc2 staged into freed spir as [128 ch][64 pts] (XOR-swizzled), then
// block-cooperative 256B-per-channel stores (full lines), BN partials -> atomics.
__global__ __launch_bounds__(256) __attribute__((amdgpu_waves_per_eu(4, 4)))
void k_main(
    const unsigned short* __restrict__ fb,   // [BNP][64] bf16
    const int* __restrict__ nidx,            // [BNP][16]
    const unsigned short* __restrict__ wmb,  // [64][64] bf16
    const unsigned short* __restrict__ wcb,  // [128][64] bf16
    float* __restrict__ out,                 // [4][128][16384], pre-BN
    float* __restrict__ stat)                // [256]: ch sums / sumsq
{
    // layout within a spir buffer (bytes): pt*64 + (ch&31)*2 + (ch>>5)*1024
    // == exactly global_load_lds's "base + lane*16" for lane=(pt<<2)|q
    __shared__ __align__(16) unsigned short spir[4][4][1024]; // 2KB/buf, 4-ring, 32KB

    const int tid  = threadIdx.x;
    const int wv   = tid >> 6;
    const int lane = tid & 63;
    const int ptc  = lane & 15;     // MFMA n / m index
    const int qg   = lane >> 4;     // quad group
    const int q4   = lane & 3;      // gather quarter

    const int g = blockIdx.x * 4 + wv;       // this wave's group (16 points)

    // ---- Wm A-fragments in registers: A[m=lane&15][k=qg*8+j (+32*ks)] ----
    short8 wmF[4][2];
    #pragma unroll
    for (int mt = 0; mt < 4; ++mt)
        #pragma unroll
        for (int ks = 0; ks < 2; ++ks)
            wmF[mt][ks] = *(const short8*)&wmb[(size_t)(mt * 16 + ptc) * CIN + qg * 8 + ks * 32];

    // ---- group's 256 neighbor indices in registers: lane holds idx[pt=lane>>2][q4*4..+3]
    i32x4 iv = *(const i32x4*)(nidx + (size_t)g * 256 + lane * 4);

    // async gather of neighbor k's 16 rows (2KB) into ring buf bf
    auto issue_gather = [&](int k, int bf) {
        // idx[pt4][k] lives in lane (pt4*4 + (k>>2)), element (k&3); k is literal
        int id = __shfl(iv[k & 3], (lane & 0x3C) | (k >> 2));
        const unsigned short* gp = fb + (size_t)id * CIN + q4 * 8;
        __builtin_amdgcn_global_load_lds(
            (const __attribute__((address_space(1))) unsigned int*)(const void*)gp,
            (__attribute__((address_space(3))) unsigned int*)(void*)&spir[wv][bf][0],
            16, 0, 0);
        __builtin_amdgcn_global_load_lds(
            (const __attribute__((address_space(1))) unsigned int*)(const void*)(gp + 32),
            (__attribute__((address_space(3))) unsigned int*)(void*)&spir[wv][bf][512],
            16, 0, 0);
    };

    issue_gather(0, 0);
    issue_gather(1, 1);
    issue_gather(2, 2);

    f32x4 pool[4];
    #pragma unroll
    for (int i = 0; i < 4; ++i) pool[i] = (f32x4){0.f, 0.f, 0.f, 0.f};

    #pragma unroll
    for (int k = 0; k < KNB; ++k) {
        const int bf = k & 3;
        if (k + 3 < KNB) issue_gather(k + 3, (k + 3) & 3);   // refill ring
        // wait for buf k's 2 loads; keep up to 3 bufs (6 ops) in flight
        if      (k <= KNB - 4) WAITVM(6);
        else if (k == KNB - 3) WAITVM(4);
        else if (k == KNB - 2) WAITVM(2);
        else                   WAITVM(0);
        __asm__ volatile("" ::: "memory");

        // ---- phase 1: score^T[d, pt] = Wm x spir^T ----
        short8 b1_0 = *(const short8*)&spir[wv][bf][      ptc * 32 + qg * 8];
        short8 b1_1 = *(const short8*)&spir[wv][bf][512 + ptc * 32 + qg * 8];
        f32x4 zero4 = (f32x4){0.f, 0.f, 0.f, 0.f};
        f32x4 a1[4];
        #pragma unroll
        for (int mt = 0; mt < 4; ++mt) {
            f32x4 t0 = __builtin_amdgcn_mfma_f32_16x16x32_bf16(wmF[mt][0], b1_0, zero4, 0, 0, 0);
            a1[mt]   = __builtin_amdgcn_mfma_f32_16x16x32_bf16(wmF[mt][1], b1_1, t0,    0, 0, 0);
        }

        // ---- softmax over d: exp IN PLACE (a1 becomes e; no extra e[16] regs) ----
        float s = 0.f;
        #pragma unroll
        for (int mt = 0; mt < 4; ++mt)
            #pragma unroll
            for (int r = 0; r < 4; ++r) {
                float x = __expf(a1[mt][r]);
                a1[mt][r] = x;
                s += x;
            }
        s += __shfl_xor(s, 16);
        s += __shfl_xor(s, 32);
        float inv = __builtin_amdgcn_rcpf(s);

        // ---- pooled[pt][d] += attn (.) spir  (pure register accumulate) ----
        #pragma unroll
        for (int mt = 0; mt < 4; ++mt) {
            // spir channels d0..d0+3, d0 = 16*mt + 4*qg (row ptc)
            u32x2 sv = *(const u32x2*)&spir[wv][bf]
                [(mt >> 1) * 512 + ptc * 32 + (mt & 1) * 16 + qg * 4];
            unsigned lo = sv[0], hi = sv[1];
            pool[mt][0] = fmaf(bf2f((unsigned short)lo),         a1[mt][0] * inv, pool[mt][0]);
            pool[mt][1] = fmaf(bf2f((unsigned short)(lo >> 16)), a1[mt][1] * inv, pool[mt][1]);
            pool[mt][2] = fmaf(bf2f((unsigned short)hi),         a1[mt][2] * inv, pool[mt][2]);
            pool[mt][3] = fmaf(bf2f((unsigned short)(hi >> 16)), a1[mt][3] * inv, pool[mt][3]);
        }
    }

    // ---- pooled -> bf16 -> LDS transpose (aliased into freed spir[wv]) -> B-frags ----
    unsigned short* pl = &spir[wv][0][0];          // 1152 shorts used, buffer is free now
    #pragma unroll
    for (int mt = 0; mt < 4; ++mt) {
        unsigned w0 = ((__float_as_uint(pool[mt][0]) + 0x8000u) >> 16) |
                      ((__float_as_uint(pool[mt][1]) + 0x8000u) & 0xFFFF0000u);
        unsigned w1 = ((__float_as_uint(pool[mt][2]) + 0x8000u) >> 16) |
                      ((__float_as_uint(pool[mt][3]) + 0x8000u) & 0xFFFF0000u);
        *(u32x2*)&pl[ptc * 72 + mt * 16 + qg * 4] = (u32x2){w0, w1};
    }
    short8 b2_0 = *(const short8*)&pl[ptc * 72 +      qg * 8];
    short8 b2_1 = *(const short8*)&pl[ptc * 72 + 32 + qg * 8];

    // ---- D[o, pt] = Wc x pooled^T, streaming bf16 Wc from global (L2-hot, 16 KB) ----
    f32x4 acc2[8];
    #pragma unroll
    for (int mt = 0; mt < 8; ++mt) {
        short8 w0 = *(const short8*)&wcb[(size_t)(mt * 16 + ptc) * CIN + qg * 8];
        short8 w1 = *(const short8*)&wcb[(size_t)(mt * 16 + ptc) * CIN + qg * 8 + 32];
        f32x4 t0 = __builtin_amdgcn_mfma_f32_16x16x32_bf16(w0, b2_0,
                                                           (f32x4){0.f,0.f,0.f,0.f}, 0, 0, 0);
        acc2[mt] = __builtin_amdgcn_mfma_f32_16x16x32_bf16(w1, b2_1, t0, 0, 0, 0);
    }

    // ---- stage block's 64x128 output tile into LDS (all 4 waves done with spir) ----
    __syncthreads();
    float* st = (float*)&spir[0][0][0];            // [128 ch][64 pts], 32 KB exact
    #pragma unroll
    for (int mt = 0; mt < 8; ++mt)
        #pragma unroll
        for (int r = 0; r < 4; ++r) {
            int ch = mt * 16 + qg * 4 + r;
            int f  = (wv * 16 + ptc) ^ ((ch & 7) << 2);    // bank swizzle, 2-way max
            st[ch * 64 + f] = acc2[mt][r];
        }
    __syncthreads();

    // ---- cooperative full-line stores (256B contiguous per channel) + BN partials ----
    const int b  = blockIdx.x >> 8;                // 64 points per block, 16384 per batch
    const int n0 = (blockIdx.x * 64) & (NPTS - 1);
    float s_acc[8], q_acc[8];
    #pragma unroll
    for (int i = 0; i < 8; ++i) {
        int flat = i * 256 + tid;
        int ch   = flat >> 4;                      // = i*16 + (tid>>4)
        int slot = flat & 15;
        int f0   = (slot * 4) ^ ((ch & 7) << 2);   // un-swizzle: yields pts slot*4..+3
        f32x4 v  = *(const f32x4*)&st[ch * 64 + f0];
        *(f32x4*)(out + (((size_t)(b * COUT + ch)) << 14) + n0 + slot * 4) = v;
        s_acc[i] = (v[0] + v[1]) + (v[2] + v[3]);
        q_acc[i] = (v[0]*v[0] + v[1]*v[1]) + (v[2]*v[2] + v[3]*v[3]);
    }
    // reduce over the 16 threads sharing each channel (aligned 16-lane groups in-wave)
    #pragma unroll
    for (int m = 1; m <= 8; m <<= 1)
        #pragma unroll
        for (int i = 0; i < 8; ++i) {
            s_acc[i] += __shfl_xor(s_acc[i], m);
            q_acc[i] += __shfl_xor(q_acc[i], m);
        }
    if ((tid & 15) == 0) {
        #pragma unroll
        for (int i = 0; i < 8; ++i) {
            int ch = i * 16 + (tid >> 4);
            atomicAdd(&stat[ch],        s_acc[i]);
            atomicAdd(&stat[COUT + ch], q_acc[i]);
        }
    }
}

// ---------------- K2: finalize stats per block + apply BN in place ----------------
__global__ __launch_bounds__(256) void k_apply(float* __restrict__ out,
                                               const float* __restrict__ stat,
                                               const float* __restrict__ gamma,
                                               const float* __restrict__ beta)
{
    __shared__ float sc[COUT], sh[COUT];
    int t = threadIdx.x;
    if (t < COUT) {
        float S = stat[t], Q = stat[COUT + t];
        float mean = S * (1.0f / BNP);
        float var  = Q * (1.0f / BNP) - mean * mean;
        float a = gamma[t] * rsqrtf(var + BN_EPS);
        sc[t] = a; sh[t] = beta[t] - mean * a;
    }
    __syncthreads();
    const int total4 = BATCH * COUT * NPTS / 4;
    for (long i = (long)blockIdx.x * 256 + t; i < total4; i += (long)gridDim.x * 256) {
        int ch = ((int)(i >> 12)) & 127;
        float4 v = ((float4*)out)[i];
        float a = sc[ch], b2 = sh[ch];
        v.x = fmaf(v.x, a, b2); v.y = fmaf(v.y, a, b2);
        v.z = fmaf(v.z, a, b2); v.w = fmaf(v.w, a, b2);
        ((float4*)out)[i] = v;
    }
}

extern "C" void kernel_launch(void* const* d_in, const int* in_sizes, int n_in,
                              void* d_out, int out_size, void* d_ws, size_t ws_size,
                              hipStream_t stream)
{
    const float* feat  = (const float*)d_in[0];
    const int*   nidx  = (const int*)  d_in[1];
    // d_in[2] = permatrix (unused); d_in[5] = b_conv (exactly absorbed by BN)
    const float* Wm    = (const float*)d_in[3];
    const float* Wc    = (const float*)d_in[4];
    const float* gamma = (const float*)d_in[6];
    const float* beta  = (const float*)d_in[7];
    float* out = (float*)d_out;

    char* ws = (char*)d_ws;
    unsigned short* fb   = (unsigned short*)ws;                       // 8.39 MB
    float*          stat = (float*)(ws + (size_t)BNP * CIN * 2);      // 1 KB
    unsigned short* wmb  = (unsigned short*)(ws + (size_t)BNP * CIN * 2 + 1024);
    unsigned short* wcb  = wmb + CIN * CIN;                           // 8 KB + 16 KB

    k_prep <<<1025, 256, 0, stream>>>(feat, fb, stat, Wm, Wc, wmb, wcb);
    k_main <<<1024, 256, 0, stream>>>(fb, nidx, wmb, wcb, out, stat);
    k_apply<<<2048, 256, 0, stream>>>(out, stat, gamma, beta);
}

// Round 5
// 219.577 us; speedup vs baseline: 1.4107x; 1.4107x over previous
//
#include <hip/hip_runtime.h>
#include <cstdint>

#define NPTS   16384
#define BATCH  4
#define BNP    65536
#define CIN    64
#define KNB    16
#define COUT   128
#define BN_EPS 1e-5f

typedef __attribute__((ext_vector_type(8))) short     short8;
typedef __attribute__((ext_vector_type(4))) float     f32x4;
typedef __attribute__((ext_vector_type(2))) unsigned  u32x2;
typedef __attribute__((ext_vector_type(4))) int       i32x4;

// wait until <= n vector-memory ops outstanding (lgkm=15, exp=7 = no wait)
#define WAITVM(n) __builtin_amdgcn_s_waitcnt(0x0F70 | (n))

__device__ __forceinline__ unsigned short f2bf(float f) {   // RNE
    unsigned u = __float_as_uint(f);
    u += 0x7FFFu + ((u >> 16) & 1u);
    return (unsigned short)(u >> 16);
}
__device__ __forceinline__ float bf2f(unsigned short h) {
    return __uint_as_float(((unsigned)h) << 16);
}

// ---- K0: feature [B][C][N] -> flat bf16 [B*N][64]; blk 1024: stat + weight cvt ----
__global__ __launch_bounds__(256) void k_prep(const float* __restrict__ feat,
                                              unsigned short* __restrict__ fb,
                                              float* __restrict__ stat,
                                              const float* __restrict__ Wm,
                                              const float* __restrict__ Wc,
                                              unsigned short* __restrict__ wmb,
                                              unsigned short* __restrict__ wcb)
{
    if (blockIdx.x == 1024) {           // aux block: zero BN accum, bf16-ify weights
        stat[threadIdx.x] = 0.f;        // 256 floats: [0..127]=sum, [128..255]=sumsq
        #pragma unroll
        for (int i = threadIdx.x; i < CIN * CIN; i += 256)       wmb[i] = f2bf(Wm[i]);
        #pragma unroll
        for (int i = threadIdx.x; i < COUT * CIN; i += 256)      wcb[i] = f2bf(Wc[i]);
        return;
    }
    __shared__ float t[CIN][CIN + 1];
    int blk = blockIdx.x;
    int b   = blk >> 8;
    int n0  = (blk & 255) << 6;
    int sub = threadIdx.x >> 6, lane = threadIdx.x & 63;
    const float* fp = feat + (size_t)b * CIN * NPTS;
    #pragma unroll
    for (int r = 0; r < CIN; r += 4) {
        int c = r + sub;
        t[c][lane] = fp[(size_t)c * NPTS + n0 + lane];     // coalesced along n
    }
    __syncthreads();
    unsigned short* ob = fb + (size_t)(b * NPTS + n0) * CIN;
    #pragma unroll
    for (int r = 0; r < CIN; r += 4) {
        int x = r + sub;
        ob[(size_t)x * CIN + lane] = f2bf(t[lane][x]);     // row n0+x, ch=lane
    }
}

// ---------------- K1: gather+attention+linear (per wave: 16 pts x 16 neigh) ------------
// ROUND-1 LOOP STRUCTURE (proven codegen: 128 VGPR, acc2 in AGPRs, no spill, 84 us):
// per k: phase1 score^T = Wm x spir^T (8 MFMA); softmax over d; P=attn*spir -> plds
// -> B-frags; phase2 acc2 += Wc x P_k (16 MFMA, pool+linear fused; MFMA is NOT the
// bottleneck at 4% util, but keeps loop state in AGPRs -> clean regalloc).
// Pool-first variants (rounds 2-4) made pool[] VALU-carried -> allocator chose 64
// VGPR + 350 MB scratch spill regardless of occupancy attributes. Do not repeat.
// New vs round 1: grid 1024 (1 group/wave, was 512x2: occupancy 19%->~50%);
// 32 KB LDS arena (spir 16K + plds 9.2K + idxl 5.1K, epilogue tile overlaid);
// bf16 weights preconverted; staged full-line epilogue stores + fused BN partials.
__global__ __launch_bounds__(256, 2) void k_main(
    const unsigned short* __restrict__ fb,   // [BNP][64] bf16
    const int* __restrict__ nidx,            // [BNP][16]
    const unsigned short* __restrict__ wmb,  // [64][64] bf16
    const unsigned short* __restrict__ wcb,  // [128][64] bf16
    float* __restrict__ out,                 // [4][128][16384], pre-BN
    float* __restrict__ stat)                // [256]: ch sums / sumsq
{
    // arena: [0,16384) spir [4 wv][2 buf][1024 u16]; [16384,25600) plds [4][1152];
    // [25600,30720) idxl [4][320]; epilogue overlays f32 st[128][64] on [0,32768)
    __shared__ __align__(16) char arena[32768];
    unsigned short* spir = (unsigned short*)arena;
    unsigned short* plds = (unsigned short*)(arena + 16384);
    int*            idxl = (int*)(arena + 25600);

    const int tid  = threadIdx.x;
    const int wv   = tid >> 6;
    const int lane = tid & 63;
    const int ptc  = lane & 15;     // MFMA n / m index
    const int qg   = lane >> 4;     // quad group
    const int pt4  = lane >> 2;     // gather row
    const int q4   = lane & 3;      // gather quarter

    const int g = blockIdx.x * 4 + wv;       // this wave's group (16 points)

    // ---- weight A-fragments in registers: A[m=lane&15][k=qg*8+j (+32*ks)] ----
    short8 wmF[4][2];
    #pragma unroll
    for (int mt = 0; mt < 4; ++mt)
        #pragma unroll
        for (int ks = 0; ks < 2; ++ks)
            wmF[mt][ks] = *(const short8*)&wmb[(size_t)(mt * 16 + ptc) * CIN + qg * 8 + ks * 32];
    short8 wcF[8][2];
    #pragma unroll
    for (int mt = 0; mt < 8; ++mt)
        #pragma unroll
        for (int ks = 0; ks < 2; ++ks)
            wcF[mt][ks] = *(const short8*)&wcb[(size_t)(mt * 16 + ptc) * CIN + qg * 8 + ks * 32];

    f32x4 acc2[8];
    #pragma unroll
    for (int i = 0; i < 8; ++i) acc2[i] = (f32x4){0.f, 0.f, 0.f, 0.f};

    // ---- stage this group's 256 neighbor indices (stride 20: 2-way max) ----
    i32x4 iv = *(const i32x4*)(nidx + (size_t)g * 256 + lane * 4);
    *(i32x4*)&idxl[wv * 320 + pt4 * 20 + q4 * 4] = iv;

    // async gather of neighbor k's 16 rows (2KB) into buf bf
    // spir buf layout (bytes): pt*64 + (ch&31)*2 + (ch>>5)*1024
    // == exactly global_load_lds's "base + lane*16" for lane=(pt<<2)|q
    auto issue_gather = [&](int k, int bf) {
        int id = idxl[wv * 320 + pt4 * 20 + k];            // 4-lane broadcast read
        const unsigned short* gp = fb + (size_t)id * CIN + q4 * 8;
        unsigned short* lp = spir + wv * 2048 + bf * 1024;
        __builtin_amdgcn_global_load_lds(
            (const __attribute__((address_space(1))) unsigned int*)(const void*)gp,
            (__attribute__((address_space(3))) unsigned int*)(void*)lp,
            16, 0, 0);
        __builtin_amdgcn_global_load_lds(
            (const __attribute__((address_space(1))) unsigned int*)(const void*)(gp + 32),
            (__attribute__((address_space(3))) unsigned int*)(void*)(lp + 512),
            16, 0, 0);
    };

    issue_gather(0, 0);
    issue_gather(1, 1);

    #pragma unroll
    for (int k = 0; k < KNB; ++k) {
        const int bf = k & 1;
        if (k < KNB - 1) WAITVM(2); else WAITVM(0);        // buf k landed
        __asm__ volatile("" ::: "memory");

        const unsigned short* sp = spir + wv * 2048 + bf * 1024;

        // ---- phase 1: score^T[d, pt] = Wm x spir^T ----
        short8 b1_0 = *(const short8*)&sp[      ptc * 32 + qg * 8];
        short8 b1_1 = *(const short8*)&sp[512 + ptc * 32 + qg * 8];
        f32x4 zero4 = (f32x4){0.f, 0.f, 0.f, 0.f};
        f32x4 a1[4];
        #pragma unroll
        for (int mt = 0; mt < 4; ++mt) {
            f32x4 t0 = __builtin_amdgcn_mfma_f32_16x16x32_bf16(wmF[mt][0], b1_0, zero4, 0, 0, 0);
            a1[mt]   = __builtin_amdgcn_mfma_f32_16x16x32_bf16(wmF[mt][1], b1_1, t0,    0, 0, 0);
        }

        // ---- softmax over d: exp in place (a1 becomes e) + xor16/xor32 ----
        float s = 0.f;
        #pragma unroll
        for (int mt = 0; mt < 4; ++mt)
            #pragma unroll
            for (int r = 0; r < 4; ++r) {
                float x = __expf(a1[mt][r]);
                a1[mt][r] = x;
                s += x;
            }
        s += __shfl_xor(s, 16);
        s += __shfl_xor(s, 32);
        float inv = __builtin_amdgcn_rcpf(s);

        // ---- P = attn (.) spir  -> plds (bf16, B-layout staging) ----
        unsigned short* pl = plds + wv * 1152;
        #pragma unroll
        for (int mt = 0; mt < 4; ++mt) {
            // spir channels d0..d0+3, d0 = 16*mt + 4*qg (row ptc)
            u32x2 sv = *(const u32x2*)&sp[(mt >> 1) * 512 + ptc * 32 + (mt & 1) * 16 + qg * 4];
            unsigned lo = sv[0], hi = sv[1];
            float p0 = bf2f((unsigned short)lo)         * (a1[mt][0] * inv);
            float p1 = bf2f((unsigned short)(lo >> 16)) * (a1[mt][1] * inv);
            float p2 = bf2f((unsigned short)hi)         * (a1[mt][2] * inv);
            float p3 = bf2f((unsigned short)(hi >> 16)) * (a1[mt][3] * inv);
            unsigned w0 = ((__float_as_uint(p0) + 0x8000u) >> 16) |
                          ((__float_as_uint(p1) + 0x8000u) & 0xFFFF0000u);
            unsigned w1 = ((__float_as_uint(p2) + 0x8000u) >> 16) |
                          ((__float_as_uint(p3) + 0x8000u) & 0xFFFF0000u);
            *(u32x2*)&pl[ptc * 72 + mt * 16 + qg * 4] = (u32x2){w0, w1};
        }

        // ---- B2 frags: P[pt=lane&15][d=qg*8+j+32ks] ----
        short8 b2_0 = *(const short8*)&pl[ptc * 72 +      qg * 8];
        short8 b2_1 = *(const short8*)&pl[ptc * 72 + 32 + qg * 8];

        if (k < KNB - 2) issue_gather(k + 2, bf);          // dbuf refill

        // ---- phase 2: acc2[o, pt] += Wc x P_k (pool+linear fused; acc2 -> AGPRs) ----
        #pragma unroll
        for (int mt = 0; mt < 8; ++mt) {
            acc2[mt] = __builtin_amdgcn_mfma_f32_16x16x32_bf16(wcF[mt][0], b2_0, acc2[mt], 0, 0, 0);
            acc2[mt] = __builtin_amdgcn_mfma_f32_16x16x32_bf16(wcF[mt][1], b2_1, acc2[mt], 0, 0, 0);
        }
    }

    // ---- stage block's 64x128 output tile into LDS (arena reused; all waves done) ----
    __syncthreads();
    float* st = (float*)arena;                     // [128 ch][64 pts], 32 KB exact
    #pragma unroll
    for (int mt = 0; mt < 8; ++mt)
        #pragma unroll
        for (int r = 0; r < 4; ++r) {
            int ch = mt * 16 + qg * 4 + r;
            int f  = (wv * 16 + ptc) ^ ((ch & 7) << 2);    // bank swizzle, low-way
            st[ch * 64 + f] = acc2[mt][r];
        }
    __syncthreads();

    // ---- cooperative full-line stores (256B contiguous per channel) + BN partials ----
    const int b  = blockIdx.x >> 8;                // 64 points per block, 16384 per batch
    const int n0 = (blockIdx.x * 64) & (NPTS - 1);
    float s_acc[8], q_acc[8];
    #pragma unroll
    for (int i = 0; i < 8; ++i) {
        int flat = i * 256 + tid;
        int ch   = flat >> 4;                      // = i*16 + (tid>>4)
        int slot = flat & 15;
        int f0   = (slot * 4) ^ ((ch & 7) << 2);   // un-swizzle: yields pts slot*4..+3
        f32x4 v  = *(const f32x4*)&st[ch * 64 + f0];
        *(f32x4*)(out + (((size_t)(b * COUT + ch)) << 14) + n0 + slot * 4) = v;
        s_acc[i] = (v[0] + v[1]) + (v[2] + v[3]);
        q_acc[i] = (v[0]*v[0] + v[1]*v[1]) + (v[2]*v[2] + v[3]*v[3]);
    }
    // reduce over the 16 threads sharing each channel (aligned 16-lane groups in-wave)
    #pragma unroll
    for (int m = 1; m <= 8; m <<= 1)
        #pragma unroll
        for (int i = 0; i < 8; ++i) {
            s_acc[i] += __shfl_xor(s_acc[i], m);
            q_acc[i] += __shfl_xor(q_acc[i], m);
        }
    if ((tid & 15) == 0) {
        #pragma unroll
        for (int i = 0; i < 8; ++i) {
            int ch = i * 16 + (tid >> 4);
            atomicAdd(&stat[ch],        s_acc[i]);
            atomicAdd(&stat[COUT + ch], q_acc[i]);
        }
    }
}

// ---------------- K2: finalize stats per block + apply BN in place ----------------
__global__ __launch_bounds__(256) void k_apply(float* __restrict__ out,
                                               const float* __restrict__ stat,
                                               const float* __restrict__ gamma,
                                               const float* __restrict__ beta)
{
    __shared__ float sc[COUT], sh[COUT];
    int t = threadIdx.x;
    if (t < COUT) {
        float S = stat[t], Q = stat[COUT + t];
        float mean = S * (1.0f / BNP);
        float var  = Q * (1.0f / BNP) - mean * mean;
        float a = gamma[t] * rsqrtf(var + BN_EPS);
        sc[t] = a; sh[t] = beta[t] - mean * a;
    }
    __syncthreads();
    const int total4 = BATCH * COUT * NPTS / 4;
    for (long i = (long)blockIdx.x * 256 + t; i < total4; i += (long)gridDim.x * 256) {
        int ch = ((int)(i >> 12)) & 127;
        float4 v = ((float4*)out)[i];
        float a = sc[ch], b2 = sh[ch];
        v.x = fmaf(v.x, a, b2); v.y = fmaf(v.y, a, b2);
        v.z = fmaf(v.z, a, b2); v.w = fmaf(v.w, a, b2);
        ((float4*)out)[i] = v;
    }
}

extern "C" void kernel_launch(void* const* d_in, const int* in_sizes, int n_in,
                              void* d_out, int out_size, void* d_ws, size_t ws_size,
                              hipStream_t stream)
{
    const float* feat  = (const float*)d_in[0];
    const int*   nidx  = (const int*)  d_in[1];
    // d_in[2] = permatrix (unused); d_in[5] = b_conv (exactly absorbed by BN)
    const float* Wm    = (const float*)d_in[3];
    const float* Wc    = (const float*)d_in[4];
    const float* gamma = (const float*)d_in[6];
    const float* beta  = (const float*)d_in[7];
    float* out = (float*)d_out;

    char* ws = (char*)d_ws;
    unsigned short* fb   = (unsigned short*)ws;                       // 8.39 MB
    float*          stat = (float*)(ws + (size_t)BNP * CIN * 2);      // 1 KB
    unsigned short* wmb  = (unsigned short*)(ws + (size_t)BNP * CIN * 2 + 1024);
    unsigned short* wcb  = wmb + CIN * CIN;                           // 8 KB + 16 KB

    k_prep <<<1025, 256, 0, stream>>>(feat, fb, stat, Wm, Wc, wmb, wcb);
    k_main <<<1024, 256, 0, stream>>>(fb, nidx, wmb, wcb, out, stat);
    k_apply<<<2048, 256, 0, stream>>>(out, stat, gamma, beta);
}